// Round 9
// baseline (2464.605 us; speedup 1.0000x reference)
//
#include <hip/hip_runtime.h>

// TemporalAttentionDecoder_three_step: B=512, T=64, M=P=256. in f32, out f32.
// R15: 1046us (best). 3 barriers/step, SMG fused, VALU 52%, occ 47%.
// R16: 2 blocks/CU A/B -> MEASURED: L2 weight transfer costs ~5.6us per
//      768KB per CU per step, ON the critical path (2-domain overlap failed
//      because both domains share the XCD L2 pipe). R15 step 17us = ~5.6 L2
//      + ~11.4 other.
// R17: R15 + traffic cut where LDS allows (calibration of the L2 model):
//      (1) e16T DELETED (-69.6KB); final ct recomputed once from global E
//          with f32 beta (R16-proven, better precision).
//      (2) first 4 k-blocks of Whh (64KB) cached in freed LDS -> per-step
//          global stream 768->704KB (-8.3%); predicted -0.47us/step (-30us).
//      (3) everything else identical to R15.
//      If -3% lands: model validated -> R18 = fp8 Whh (-33% traffic, -11%).
// f32 state: creg (j<256); f16: h,c,y1,ct,weights; dots accumulate f32.

typedef unsigned short u16;
typedef unsigned int u32;
typedef _Float16 half_t;
typedef half_t h2 __attribute__((ext_vector_type(2)));

#define BB 512
#define TT 64
#define MM 256
#define YS 264   // y1l row stride (u16); measured conflict-free (R6/R7)
#define NROW 2
#define NTH 1024

// ws layout (u16), all k-blocked n-major [kb][n][8]:
//   WdT8 [64kb][256n][8]  @ 0       (131072)
//   WhhT8[32kb][1024n][8] @ 131072  (262144)
//   WyT8 [64kb][256n][8]  @ 393216  (131072)
#define WD16_OFF  0
#define WHH16_OFF 131072
#define WY16_OFF  393216
#define WQ_ELEMS  524288
#define WQ_BYTES  (WQ_ELEMS * 2)

struct H8 { h2 p[4]; };   // 16B = 8 f16

#if defined(__has_builtin)
#if __has_builtin(__builtin_amdgcn_fdot2)
#define FDOT2(a, b, c) __builtin_amdgcn_fdot2((a), (b), (c), false)
#endif
#endif
#ifndef FDOT2
__device__ __forceinline__ float FDOT2(h2 a, h2 b, float c) {
  return c + (float)a[0] * (float)b[0] + (float)a[1] * (float)b[1];
}
#endif

__device__ __forceinline__ float dot8(const H8 w, const H8 a, float acc) {
  acc = FDOT2(w.p[0], a.p[0], acc);
  acc = FDOT2(w.p[1], a.p[1], acc);
  acc = FDOT2(w.p[2], a.p[2], acc);
  acc = FDOT2(w.p[3], a.p[3], acc);
  return acc;
}
__device__ __forceinline__ u16 f2h(float f) {
  union { half_t h; u16 u; } x; x.h = (half_t)f; return x.u;
}
__device__ __forceinline__ u32 pack2h(float a, float b) {
  union { h2 h; u32 u; } x;
  x.h[0] = (half_t)a; x.h[1] = (half_t)b;
  return x.u;
}
__device__ __forceinline__ h2 u2h2(u32 u) {
  union { u32 u; h2 h; } x; x.u = u; return x.h;
}
__device__ __forceinline__ void unpackH8(const H8 v, float f[8]) {
#pragma unroll
  for (int i = 0; i < 8; ++i) f[i] = (float)v.p[i >> 1][i & 1];
}
__device__ __forceinline__ void ldf8(const float* p, float f[8]) {
  float4 a = *(const float4*)p;
  float4 b = *(const float4*)(p + 4);
  f[0]=a.x; f[1]=a.y; f[2]=a.z; f[3]=a.w;
  f[4]=b.x; f[5]=b.y; f[6]=b.z; f[7]=b.w;
}
__device__ __forceinline__ float tanh_fast(float x) {
  float e = __builtin_amdgcn_exp2f(x * 2.885390081777927f);
  return 1.0f - 2.0f * __builtin_amdgcn_rcpf(1.0f + e);
}
__device__ __forceinline__ float sigmoid_fast(float x) {
  float e = __builtin_amdgcn_exp2f(x * -1.4426950408889634f);
  return __builtin_amdgcn_rcpf(1.0f + e);
}

// ---- prep: f32 -> f16, k-blocked n-major ----
__global__ __launch_bounds__(256) void prep_kernel(
    const float* __restrict__ Wd, const float* __restrict__ Whh,
    const float* __restrict__ Wy, u16* __restrict__ o) {
  int i = blockIdx.x * 256 + threadIdx.x;   // 0..524287
  float v;
  if (i < WHH16_OFF) {
    int ki = i & 7, n = (i >> 3) & 255, kb = i >> 11;
    v = Wd[n * 512 + kb * 8 + ki];
  } else if (i < WY16_OFF) {
    int r = i - WHH16_OFF;
    int ki = r & 7, n = (r >> 3) & 1023, kb = r >> 13;
    v = Whh[n * 256 + kb * 8 + ki];
  } else {
    int r = i - WY16_OFF;
    int ki = r & 7, n = (r >> 3) & 255, kb = r >> 11;
    v = Wy[n * 512 + kb * 8 + ki];
  }
  o[i] = f2h(v);
}

template <int WQ>
__global__ __launch_bounds__(NTH, 4) void scan_kernel(
    const float* __restrict__ E,      // (B,T,M)
    const float* __restrict__ yin,    // (B,T,1)
    const float* __restrict__ tar,    // (B,2)
    const int*   __restrict__ train,  // (1)
    const void*  __restrict__ Wd_q,   // WQ1: WdT8 f16 | WQ0: f32 row-major
    const float* __restrict__ Wd_b,
    const float* __restrict__ Ud_w,   // (256,256) f32
    const float* __restrict__ vd_w,
    const float* __restrict__ wt_w,   // (257)
    const float* __restrict__ wt_b,
    const void*  __restrict__ Wy_q,
    const float* __restrict__ Wy_b,
    const float* __restrict__ vy_w,
    const float* __restrict__ vy_b,
    const float* __restrict__ Wih,    // (1024)
    const void*  __restrict__ Whh_q,
    const float* __restrict__ bih,
    const float* __restrict__ bhh,
    float* __restrict__ out)          // (3*B)
{
  __shared__ __align__(16) u16   y1l[NROW][TT * YS];   // 66KB f16 y1
  __shared__ __align__(16) u16   whhc[4 * 1024 * 8];   // 64KB Whh kb 0..3 cache
  __shared__ __align__(16) u32   hs16[NROW][256];      // h pairs [0,128), c [128,256)
  __shared__ __align__(16) u32   ctx16p[NROW][128];    // final ct f16 pairs
  __shared__ __align__(16) float px1[8][MM];   // x1 quarters [(r<<2)|q]; head reuse
  __shared__ __align__(16) u32   pgs32[8][MM]; // gate partials [(g<<1)|half], r0|r1<<16
  __shared__ __align__(16) float lpart[NROW][4][TT];
  __shared__ __align__(16) float bet[NROW][TT];        // final beta (f32)
  __shared__ __align__(16) float ysh[NROW][TT];
  __shared__ __align__(16) float ewl[NROW][TT];        // ew[t] = E[t].wt
  __shared__ float red[16];
  __shared__ float sc[NROW];

  const int j   = threadIdx.x;         // 0..1023
  const int n   = j & 255;             // output index
  const int grp = j >> 8;              // group 0..3 (wave-aligned)
  const int wv  = j >> 6;              // wave 0..15
  const int b0  = blockIdx.x * NROW;   // batch rows b0, b0+1

  if (j < 512) ((u32*)hs16)[j] = 0;
  float creg0 = 0.f, creg1 = 0.f;      // live in j<256 threads

  // gate constants (consumed by j<256)
  const float wih0 = Wih[n],       wih1 = Wih[n + 256];
  const float wih2 = Wih[n + 512], wih3 = Wih[n + 768];
  const float bb0 = bih[n]       + bhh[n];
  const float bb1 = bih[n + 256] + bhh[n + 256];
  const float bb2 = bih[n + 512] + bhh[n + 512];
  const float bb3 = bih[n + 768] + bhh[n + 768];
  const float wtM = wt_w[MM], wtb = wt_b[0];

  // ---- stage Whh kb 0..3 into LDS cache (WQ path) ----
  if (WQ) {
    const u32* __restrict__ src = (const u32*)Whh_q;
    u32* __restrict__ dst = (u32*)whhc;
    for (int i = j; i < 16384; i += NTH) dst[i] = src[i];
  }

  // ---- stage yin rows + ew[t] = E[t].wt (loop-invariant) ----
  if (j < NROW * TT) {
    const int r = j >> 6, t = j & 63;
    ysh[r][t] = yin[(size_t)(b0 + r) * TT + t];
    const float* __restrict__ Er = E + ((size_t)(b0 + r) * TT + t) * MM;
    float acc = 0.f;
    for (int m0 = 0; m0 < MM; m0 += 8) {
      float e[8], w[8];
      ldf8(Er + m0, e); ldf8(wt_w + m0, w);
#pragma unroll
      for (int m = 0; m < 8; ++m) acc = fmaf(e[m], w[m], acc);
    }
    ewl[r][t] = acc;
  }

  // ---- y1 into LDS: thread (grp,n): row grp>>1, t-half grp&1, column n ----
  {
    const int rs = grp >> 1, ths = grp & 1;
    const float* __restrict__ Eb = E + (size_t)(b0 + rs) * TT * MM;
    const float* __restrict__ Uj = Ud_w + (size_t)n * MM;
    for (int t0 = ths * 32; t0 < ths * 32 + 32; t0 += 16) {
      float acc[16];
#pragma unroll
      for (int i = 0; i < 16; ++i) acc[i] = 0.f;
      for (int m0 = 0; m0 < MM; m0 += 8) {
        float w[8]; ldf8(Uj + m0, w);
#pragma unroll
        for (int tt = 0; tt < 16; ++tt) {
          float e[8]; ldf8(Eb + (size_t)(t0 + tt) * MM + m0, e);
#pragma unroll
          for (int mm = 0; mm < 8; ++mm) acc[tt] = fmaf(e[mm], w[mm], acc[tt]);
        }
      }
#pragma unroll
      for (int tt = 0; tt < 16; ++tt)
        y1l[rs][(t0 + tt) * YS + n] = f2h(acc[tt]);
    }
  }
  __syncthreads();

  // ---- gates: torch LSTMCell order i,f,g,o; j<256 threads, both rows ----
  auto gates_apply = [&](int r, float gi, float gf, float gg, float go,
                         float ytil) {
    gi += ytil * wih0 + bb0;
    gf += ytil * wih1 + bb1;
    gg += ytil * wih2 + bb2;
    go += ytil * wih3 + bb3;
    float& cr = r ? creg1 : creg0;
    float c = sigmoid_fast(gf) * cr + sigmoid_fast(gi) * tanh_fast(gg);
    float h = sigmoid_fast(go) * tanh_fast(c);
    cr = c;
    u16* hsu = (u16*)hs16[r];
    hsu[n] = f2h(h);
    hsu[256 + n] = f2h(c);
  };

  // ---- S2: Whh@h all 4 gates x both rows; waves 8-15; kb<4 from LDS ----
  auto whh_gates = [&]() {
    if (wv >= 8) {
      const int jj = j - 512;
      const int n2 = jj & 255, half = jj >> 8;   // k-half
      float a00 = 0, a01 = 0, a10 = 0, a11 = 0;
      float a20 = 0, a21 = 0, a30 = 0, a31 = 0;
      if (WQ) {
        const u16* __restrict__ base =
            (const u16*)Whh_q + ((size_t)(half * 16) * 1024 + n2) * 8;
#pragma unroll
        for (int i = 0; i < 16; ++i) {
          H8 w0, w1, w2, w3;
          if (i < 4 && half == 0) {
            const u16* p = whhc + ((size_t)i * 1024 + n2) * 8;
            w0 = *(const H8*)p;
            w1 = *(const H8*)(p + 2048);
            w2 = *(const H8*)(p + 4096);
            w3 = *(const H8*)(p + 6144);
          } else {
            const u16* p = base + (size_t)i * 8192;
            w0 = *(const H8*)p;
            w1 = *(const H8*)(p + 2048);
            w2 = *(const H8*)(p + 4096);
            w3 = *(const H8*)(p + 6144);
          }
          const int kb = half * 16 + i;
          H8 h0v = *(const H8*)&hs16[0][kb * 4];
          H8 h1v = *(const H8*)&hs16[1][kb * 4];
          a00 = dot8(w0, h0v, a00); a01 = dot8(w0, h1v, a01);
          a10 = dot8(w1, h0v, a10); a11 = dot8(w1, h1v, a11);
          a20 = dot8(w2, h0v, a20); a21 = dot8(w2, h1v, a21);
          a30 = dot8(w3, h0v, a30); a31 = dot8(w3, h1v, a31);
        }
      } else {
        const float* __restrict__ base =
            (const float*)Whh_q + (size_t)n2 * 256 + half * 128;
#pragma unroll 2
        for (int i = 0; i < 16; ++i) {
          const int kb = half * 16 + i;
          H8 h0v = *(const H8*)&hs16[0][kb * 4];
          H8 h1v = *(const H8*)&hs16[1][kb * 4];
          float hf0[8], hf1[8]; unpackH8(h0v, hf0); unpackH8(h1v, hf1);
          float w0[8], w1[8], w2[8], w3[8];
          ldf8(base + i * 8, w0);
          ldf8(base + 256 * 256 + i * 8, w1);
          ldf8(base + 512 * 256 + i * 8, w2);
          ldf8(base + 768 * 256 + i * 8, w3);
#pragma unroll
          for (int m = 0; m < 8; ++m) {
            a00 = fmaf(hf0[m], w0[m], a00); a01 = fmaf(hf1[m], w0[m], a01);
            a10 = fmaf(hf0[m], w1[m], a10); a11 = fmaf(hf1[m], w1[m], a11);
            a20 = fmaf(hf0[m], w2[m], a20); a21 = fmaf(hf1[m], w2[m], a21);
            a30 = fmaf(hf0[m], w3[m], a30); a31 = fmaf(hf1[m], w3[m], a31);
          }
        }
      }
      pgs32[(0 << 1) | half][n2] = pack2h(a00, a01);
      pgs32[(1 << 1) | half][n2] = pack2h(a10, a11);
      pgs32[(2 << 1) | half][n2] = pack2h(a20, a21);
      pgs32[(3 << 1) | half][n2] = pack2h(a30, a31);
    }
  };

  // ---- G: combine pgs32 halves + LSTM gates (j<256, both rows) ----
  auto gates_combine_apply = [&](float yt0, float yt1) {
    h2 i0 = u2h2(pgs32[0][n]), i1 = u2h2(pgs32[1][n]);
    h2 f0 = u2h2(pgs32[2][n]), f1 = u2h2(pgs32[3][n]);
    h2 g0 = u2h2(pgs32[4][n]), g1 = u2h2(pgs32[5][n]);
    h2 o0 = u2h2(pgs32[6][n]), o1 = u2h2(pgs32[7][n]);
    gates_apply(0, (float)i0[0] + (float)i1[0], (float)f0[0] + (float)f1[0],
                (float)g0[0] + (float)g1[0], (float)o0[0] + (float)o1[0], yt0);
    gates_apply(1, (float)i0[1] + (float)i1[1], (float)f0[1] + (float)f1[1],
                (float)g0[1] + (float)g1[1], (float)o0[1] + (float)o1[1], yt1);
  };

  // ---- head: grp = (row<<1)|seg; seg0 = h-seg, seg1 = ct-seg ----
  auto head_store = [&](int outIdx) {
    float p = 0.f;
    const int rr = grp >> 1, seg = grp & 1;
    const u32* st = seg ? ctx16p[rr] : hs16[rr];
    if (WQ) {
      const u16* pw = (const u16*)Wy_q + ((size_t)(seg * 32) * 256 + n) * 8;
#pragma unroll 2
      for (int kb = 0; kb < 32; ++kb) {
        H8 w = *(const H8*)pw; pw += 2048;
        H8 s = *(const H8*)&st[kb * 4];
        p = dot8(w, s, p);
      }
    } else {
      const float* W = (const float*)Wy_q + (size_t)n * 512 + seg * 256;
#pragma unroll 2
      for (int kb = 0; kb < 32; ++kb) {
        H8 sv = *(const H8*)&st[kb * 4];
        float sf[8]; unpackH8(sv, sf);
        float w[8]; ldf8(W + kb * 8, w);
#pragma unroll
        for (int i = 0; i < 8; ++i) p = fmaf(sf[i], w[i], p);
      }
    }
    if (grp) px1[grp - 1][n] = p;   // px1 free after scan; reuse as head parts
    __syncthreads();
    if (grp == 0) {
      float q0 = (p + px1[0][n] + Wy_b[n]) * vy_w[n];
      float q1 = (px1[1][n] + px1[2][n] + Wy_b[n]) * vy_w[n];
#pragma unroll
      for (int off = 32; off; off >>= 1) {
        q0 += __shfl_xor(q0, off, 64);
        q1 += __shfl_xor(q1, off, 64);
      }
      if ((j & 63) == 0) { red[wv] = q0; red[8 + wv] = q1; }
    }
    __syncthreads();
    if (j == 0) {
      float o0 = red[0] + red[1] + red[2] + red[3] + vy_b[0];
      float o1 = red[8] + red[9] + red[10] + red[11] + vy_b[0];
      out[(size_t)outIdx * BB + b0] = o0;
      out[(size_t)outIdx * BB + b0 + 1] = o1;
      sc[0] = o0; sc[1] = o1;
    }
    __syncthreads();
  };

  // ================= scan over T steps =================
  for (int step = 0; step < TT; ++step) {
    // ---- S1: x1 = Wd.[h|c], 4-way split-k (all waves) ----
    {
      float ax0 = 0.f, ax1 = 0.f;
      if (WQ) {
        const u16* pd = (const u16*)Wd_q + ((size_t)(grp * 16) * 256 + n) * 8;
#pragma unroll 4
        for (int i = 0; i < 16; ++i) {
          H8 w = *(const H8*)pd; pd += 2048;
          const int kb = grp * 16 + i;
          H8 s0 = *(const H8*)&hs16[0][kb * 4];
          H8 s1 = *(const H8*)&hs16[1][kb * 4];
          ax0 = dot8(w, s0, ax0);
          ax1 = dot8(w, s1, ax1);
        }
      } else {
        const float* pd = (const float*)Wd_q + (size_t)n * 512 + grp * 128;
#pragma unroll 2
        for (int i = 0; i < 16; ++i) {
          const int kb = grp * 16 + i;
          H8 s0v = *(const H8*)&hs16[0][kb * 4];
          H8 s1v = *(const H8*)&hs16[1][kb * 4];
          float f0[8], f1[8]; unpackH8(s0v, f0); unpackH8(s1v, f1);
          float w[8]; ldf8(pd + i * 8, w);
#pragma unroll
          for (int m = 0; m < 8; ++m) {
            ax0 = fmaf(f0[m], w[m], ax0);
            ax1 = fmaf(f1[m], w[m], ax1);
          }
        }
      }
      if (grp == 0) { float b = Wd_b[n]; ax0 += b; ax1 += b; }
      px1[grp][n] = ax0;
      px1[4 + grp][n] = ax1;
    }
    __syncthreads();

    // ---- B1 (waves 0-7) PARALLEL S2 (waves 8-15) ----
    if (wv < 8) {
      const int r = j >> 8, e4 = (j >> 6) & 3, t = j & 63;
      const int mb = e4 * 64;
      const u16* __restrict__ yrow = &y1l[r][t * YS + mb];
      const float* __restrict__ p0 = &px1[(r << 2) | 0][mb];
      const float* __restrict__ p1 = &px1[(r << 2) | 1][mb];
      const float* __restrict__ p2 = &px1[(r << 2) | 2][mb];
      const float* __restrict__ p3 = &px1[(r << 2) | 3][mb];
      const float* __restrict__ vp = vd_w + mb;
      float lp = 0.f;
#pragma unroll 2
      for (int m0 = 0; m0 < 64; m0 += 8) {
        float xa[8], xb[8], xc[8], xd[8], vf[8], yf[8];
        ldf8(p0 + m0, xa); ldf8(p1 + m0, xb);
        ldf8(p2 + m0, xc); ldf8(p3 + m0, xd);
        H8 yv = *(const H8*)(yrow + m0); unpackH8(yv, yf);
        ldf8(vp + m0, vf);
#pragma unroll
        for (int mm = 0; mm < 8; ++mm) {
          float z = tanh_fast(xa[mm] + xb[mm] + xc[mm] + xd[mm] + yf[mm]);
          lp = fmaf(z, vf[mm], lp);
        }
      }
      lpart[r][e4][t] = lp;
    } else {
      whh_gates();
    }
    __syncthreads();

    // ---- SMG: in-wave softmax + ytil + gates (waves 0-3, both rows) ----
    if (j < 256) {
      const int t = j & 63;
      float l0 = lpart[0][0][t] + lpart[0][1][t] + lpart[0][2][t] +
                 lpart[0][3][t];
      float l1 = lpart[1][0][t] + lpart[1][1][t] + lpart[1][2][t] +
                 lpart[1][3][t];
      float m0v = l0, m1v = l1;
#pragma unroll
      for (int off = 32; off; off >>= 1) {
        m0v = fmaxf(m0v, __shfl_xor(m0v, off, 64));
        m1v = fmaxf(m1v, __shfl_xor(m1v, off, 64));
      }
      float e0 = __builtin_amdgcn_exp2f((l0 - m0v) * 1.4426950408889634f);
      float e1 = __builtin_amdgcn_exp2f((l1 - m1v) * 1.4426950408889634f);
      float se0 = e0, sy0 = e0 * ewl[0][t];
      float se1 = e1, sy1 = e1 * ewl[1][t];
#pragma unroll
      for (int off = 32; off; off >>= 1) {
        se0 += __shfl_xor(se0, off, 64); sy0 += __shfl_xor(sy0, off, 64);
        se1 += __shfl_xor(se1, off, 64); sy1 += __shfl_xor(sy1, off, 64);
      }
      float yt0 = sy0 * __builtin_amdgcn_rcpf(se0) + ysh[0][step] * wtM + wtb;
      float yt1 = sy1 * __builtin_amdgcn_rcpf(se1) + ysh[1][step] * wtM + wtb;
      gates_combine_apply(yt0, yt1);
    }
    __syncthreads();
  }

  // ================= finals =================
  // final beta (f32) from last step's lpart (waves 0-1)
  if (j < NROW * TT) {
    const int r = j >> 6, t = j & 63;
    float l = lpart[r][0][t] + lpart[r][1][t] + lpart[r][2][t] +
              lpart[r][3][t];
    float mx = l;
#pragma unroll
    for (int off = 32; off; off >>= 1) mx = fmaxf(mx, __shfl_xor(mx, off, 64));
    float e = __builtin_amdgcn_exp2f((l - mx) * 1.4426950408889634f);
    float sm = e;
#pragma unroll
    for (int off = 32; off; off >>= 1) sm += __shfl_xor(sm, off, 64);
    bet[r][t] = e * __builtin_amdgcn_rcpf(sm);
  }
  __syncthreads();

  // ct[n] = sum_t bet[t]*E[t][n] from GLOBAL E (f32; coalesced per t)
  if (j < 512) {
    const int r = j >> 8;
    const float* __restrict__ Eb = E + (size_t)(b0 + r) * TT * MM + n;
    float acc = 0.f;
#pragma unroll 8
    for (int t = 0; t < TT; ++t)
      acc = fmaf(bet[r][t], Eb[(size_t)t * MM], acc);
    ((u16*)ctx16p[r])[n] = f2h(acc);
    float p = acc * wt_w[n];
#pragma unroll
    for (int off = 32; off; off >>= 1) p += __shfl_xor(p, off, 64);
    if ((j & 63) == 0) red[wv] = p;   // wv 0..3 -> r0, 4..7 -> r1
  }
  __syncthreads();
  const float ctd0 = red[0] + red[1] + red[2] + red[3];
  const float ctd1 = red[4] + red[5] + red[6] + red[7];

  head_store(0);  // y_Tp1 (sc[] holds it for train==0 feedback)

  const int tr = train[0];
  for (int e = 0; e < 2; ++e) {
    whh_gates();            // waves 8-15: Whh@h -> pgs32
    __syncthreads();
    if (j < 256) {
      float inp0 = tr ? tar[(size_t)b0 * 2 + e] : sc[0];
      float inp1 = tr ? tar[(size_t)(b0 + 1) * 2 + e] : sc[1];
      float yt0 = ctd0 + inp0 * wtM + wtb;
      float yt1 = ctd1 + inp1 * wtM + wtb;
      gates_combine_apply(yt0, yt1);
    }
    __syncthreads();
    head_store(1 + e);
  }
}

extern "C" void kernel_launch(void* const* d_in, const int* in_sizes, int n_in,
                              void* d_out, int out_size, void* d_ws, size_t ws_size,
                              hipStream_t stream) {
  const float* E     = (const float*)d_in[0];
  const float* yin   = (const float*)d_in[1];
  const float* tar   = (const float*)d_in[2];
  const int*   train = (const int*)d_in[3];
  const float* Wd_w  = (const float*)d_in[4];
  const float* Wd_b  = (const float*)d_in[5];
  const float* Ud_w  = (const float*)d_in[6];
  const float* vd_w  = (const float*)d_in[7];
  const float* wt_w  = (const float*)d_in[8];
  const float* wt_b  = (const float*)d_in[9];
  const float* Wy_w  = (const float*)d_in[10];
  const float* Wy_b  = (const float*)d_in[11];
  const float* vy_w  = (const float*)d_in[12];
  const float* vy_b  = (const float*)d_in[13];
  const float* Wih   = (const float*)d_in[14];
  const float* Whh   = (const float*)d_in[15];
  const float* bih   = (const float*)d_in[16];
  const float* bhh   = (const float*)d_in[17];

  float* out = (float*)d_out;

  if (ws_size >= (size_t)WQ_BYTES) {
    u16* wq = (u16*)d_ws;
    prep_kernel<<<dim3(WQ_ELEMS / 256), dim3(256), 0, stream>>>(
        Wd_w, Whh, Wy_w, wq);
    scan_kernel<1><<<dim3(BB / NROW), dim3(NTH), 0, stream>>>(
        E, yin, tar, train, wq + WD16_OFF, Wd_b, Ud_w, vd_w, wt_w, wt_b,
        wq + WY16_OFF, Wy_b, vy_w, vy_b, Wih, wq + WHH16_OFF, bih, bhh, out);
  } else {
    scan_kernel<0><<<dim3(BB / NROW), dim3(NTH), 0, stream>>>(
        E, yin, tar, train, Wd_w, Wd_b, Ud_w, vd_w, wt_w, wt_b,
        Wy_w, Wy_b, vy_w, vy_b, Wih, Whh, bih, bhh, out);
  }

  (void)in_sizes; (void)n_in; (void)out_size;
}

// Round 10
// 1030.920 us; speedup vs baseline: 2.3907x; 2.3907x over previous
//
#include <hip/hip_runtime.h>

// TemporalAttentionDecoder_three_step: B=512, T=64, M=P=256. in f32, out f32.
// R15: 1046us (best). 3 barriers/step, SMG fused, VALU 52%, occ 47%.
// R16: A/B MEASURED: per-CU L2 weight stream ~5.6us/768KB/step, on the
//      critical path (2-domain overlap shares the XCD L2 pipe -> failed).
// R17: LDS-cache calibration CORRUPTED by spill #3: per-iteration
//      `if(i<4 && half==0)` in unrolled S2 kept both paths' state live ->
//      over the wg=1024 64-VGPR wall -> scratch (WRITE 171MB). RULE: no
//      conditionals/extra live state inside unrolled hot loops at wg=1024.
// R18: same experiment, spill-free: S2 PEELED into wave-uniform paths
//      (half==0: 4 LDS iters + 12 global; half==1: 16 global). e16T deleted
//      (-69.6KB, final ct from global E w/ f32 beta, R16/R17-proven);
//      64KB Whh kb0..3 LDS cache. Predicted -0.4us/step (~-28us).
// f32 state: creg (j<256); f16: h,c,y1,ct,weights; dots accumulate f32.

typedef unsigned short u16;
typedef unsigned int u32;
typedef _Float16 half_t;
typedef half_t h2 __attribute__((ext_vector_type(2)));

#define BB 512
#define TT 64
#define MM 256
#define YS 264   // y1l row stride (u16); measured conflict-free (R6/R7)
#define NROW 2
#define NTH 1024

// ws layout (u16), all k-blocked n-major [kb][n][8]:
//   WdT8 [64kb][256n][8]  @ 0       (131072)
//   WhhT8[32kb][1024n][8] @ 131072  (262144)
//   WyT8 [64kb][256n][8]  @ 393216  (131072)
#define WD16_OFF  0
#define WHH16_OFF 131072
#define WY16_OFF  393216
#define WQ_ELEMS  524288
#define WQ_BYTES  (WQ_ELEMS * 2)

struct H8 { h2 p[4]; };   // 16B = 8 f16

#if defined(__has_builtin)
#if __has_builtin(__builtin_amdgcn_fdot2)
#define FDOT2(a, b, c) __builtin_amdgcn_fdot2((a), (b), (c), false)
#endif
#endif
#ifndef FDOT2
__device__ __forceinline__ float FDOT2(h2 a, h2 b, float c) {
  return c + (float)a[0] * (float)b[0] + (float)a[1] * (float)b[1];
}
#endif

__device__ __forceinline__ float dot8(const H8 w, const H8 a, float acc) {
  acc = FDOT2(w.p[0], a.p[0], acc);
  acc = FDOT2(w.p[1], a.p[1], acc);
  acc = FDOT2(w.p[2], a.p[2], acc);
  acc = FDOT2(w.p[3], a.p[3], acc);
  return acc;
}
__device__ __forceinline__ u16 f2h(float f) {
  union { half_t h; u16 u; } x; x.h = (half_t)f; return x.u;
}
__device__ __forceinline__ u32 pack2h(float a, float b) {
  union { h2 h; u32 u; } x;
  x.h[0] = (half_t)a; x.h[1] = (half_t)b;
  return x.u;
}
__device__ __forceinline__ h2 u2h2(u32 u) {
  union { u32 u; h2 h; } x; x.u = u; return x.h;
}
__device__ __forceinline__ void unpackH8(const H8 v, float f[8]) {
#pragma unroll
  for (int i = 0; i < 8; ++i) f[i] = (float)v.p[i >> 1][i & 1];
}
__device__ __forceinline__ void ldf8(const float* p, float f[8]) {
  float4 a = *(const float4*)p;
  float4 b = *(const float4*)(p + 4);
  f[0]=a.x; f[1]=a.y; f[2]=a.z; f[3]=a.w;
  f[4]=b.x; f[5]=b.y; f[6]=b.z; f[7]=b.w;
}
__device__ __forceinline__ float tanh_fast(float x) {
  float e = __builtin_amdgcn_exp2f(x * 2.885390081777927f);
  return 1.0f - 2.0f * __builtin_amdgcn_rcpf(1.0f + e);
}
__device__ __forceinline__ float sigmoid_fast(float x) {
  float e = __builtin_amdgcn_exp2f(x * -1.4426950408889634f);
  return __builtin_amdgcn_rcpf(1.0f + e);
}

// ---- prep: f32 -> f16, k-blocked n-major ----
__global__ __launch_bounds__(256) void prep_kernel(
    const float* __restrict__ Wd, const float* __restrict__ Whh,
    const float* __restrict__ Wy, u16* __restrict__ o) {
  int i = blockIdx.x * 256 + threadIdx.x;   // 0..524287
  float v;
  if (i < WHH16_OFF) {
    int ki = i & 7, n = (i >> 3) & 255, kb = i >> 11;
    v = Wd[n * 512 + kb * 8 + ki];
  } else if (i < WY16_OFF) {
    int r = i - WHH16_OFF;
    int ki = r & 7, n = (r >> 3) & 1023, kb = r >> 13;
    v = Whh[n * 256 + kb * 8 + ki];
  } else {
    int r = i - WY16_OFF;
    int ki = r & 7, n = (r >> 3) & 255, kb = r >> 11;
    v = Wy[n * 512 + kb * 8 + ki];
  }
  o[i] = f2h(v);
}

template <int WQ>
__global__ __launch_bounds__(NTH, 4) void scan_kernel(
    const float* __restrict__ E,      // (B,T,M)
    const float* __restrict__ yin,    // (B,T,1)
    const float* __restrict__ tar,    // (B,2)
    const int*   __restrict__ train,  // (1)
    const void*  __restrict__ Wd_q,   // WQ1: WdT8 f16 | WQ0: f32 row-major
    const float* __restrict__ Wd_b,
    const float* __restrict__ Ud_w,   // (256,256) f32
    const float* __restrict__ vd_w,
    const float* __restrict__ wt_w,   // (257)
    const float* __restrict__ wt_b,
    const void*  __restrict__ Wy_q,
    const float* __restrict__ Wy_b,
    const float* __restrict__ vy_w,
    const float* __restrict__ vy_b,
    const float* __restrict__ Wih,    // (1024)
    const void*  __restrict__ Whh_q,
    const float* __restrict__ bih,
    const float* __restrict__ bhh,
    float* __restrict__ out)          // (3*B)
{
  __shared__ __align__(16) u16   y1l[NROW][TT * YS];   // 66KB f16 y1
  __shared__ __align__(16) u16   whhc[4 * 1024 * 8];   // 64KB Whh kb 0..3 cache
  __shared__ __align__(16) u32   hs16[NROW][256];      // h pairs [0,128), c [128,256)
  __shared__ __align__(16) u32   ctx16p[NROW][128];    // final ct f16 pairs
  __shared__ __align__(16) float px1[8][MM];   // x1 quarters [(r<<2)|q]; head reuse
  __shared__ __align__(16) u32   pgs32[8][MM]; // gate partials [(g<<1)|half], r0|r1<<16
  __shared__ __align__(16) float lpart[NROW][4][TT];
  __shared__ __align__(16) float bet[NROW][TT];        // final beta (f32)
  __shared__ __align__(16) float ysh[NROW][TT];
  __shared__ __align__(16) float ewl[NROW][TT];        // ew[t] = E[t].wt
  __shared__ float red[16];
  __shared__ float sc[NROW];

  const int j   = threadIdx.x;         // 0..1023
  const int n   = j & 255;             // output index
  const int grp = j >> 8;              // group 0..3 (wave-aligned)
  const int wv  = j >> 6;              // wave 0..15
  const int b0  = blockIdx.x * NROW;   // batch rows b0, b0+1

  if (j < 512) ((u32*)hs16)[j] = 0;
  float creg0 = 0.f, creg1 = 0.f;      // live in j<256 threads

  // gate constants (consumed by j<256)
  const float wih0 = Wih[n],       wih1 = Wih[n + 256];
  const float wih2 = Wih[n + 512], wih3 = Wih[n + 768];
  const float bb0 = bih[n]       + bhh[n];
  const float bb1 = bih[n + 256] + bhh[n + 256];
  const float bb2 = bih[n + 512] + bhh[n + 512];
  const float bb3 = bih[n + 768] + bhh[n + 768];
  const float wtM = wt_w[MM], wtb = wt_b[0];

  // ---- stage Whh kb 0..3 into LDS cache (WQ path; coalesced copy) ----
  if (WQ) {
    const u32* __restrict__ src = (const u32*)Whh_q;
    u32* __restrict__ dst = (u32*)whhc;
    for (int i = j; i < 16384; i += NTH) dst[i] = src[i];
  }

  // ---- stage yin rows + ew[t] = E[t].wt (loop-invariant) ----
  if (j < NROW * TT) {
    const int r = j >> 6, t = j & 63;
    ysh[r][t] = yin[(size_t)(b0 + r) * TT + t];
    const float* __restrict__ Er = E + ((size_t)(b0 + r) * TT + t) * MM;
    float acc = 0.f;
    for (int m0 = 0; m0 < MM; m0 += 8) {
      float e[8], w[8];
      ldf8(Er + m0, e); ldf8(wt_w + m0, w);
#pragma unroll
      for (int m = 0; m < 8; ++m) acc = fmaf(e[m], w[m], acc);
    }
    ewl[r][t] = acc;
  }

  // ---- y1 into LDS: thread (grp,n): row grp>>1, t-half grp&1, column n ----
  {
    const int rs = grp >> 1, ths = grp & 1;
    const float* __restrict__ Eb = E + (size_t)(b0 + rs) * TT * MM;
    const float* __restrict__ Uj = Ud_w + (size_t)n * MM;
    for (int t0 = ths * 32; t0 < ths * 32 + 32; t0 += 16) {
      float acc[16];
#pragma unroll
      for (int i = 0; i < 16; ++i) acc[i] = 0.f;
      for (int m0 = 0; m0 < MM; m0 += 8) {
        float w[8]; ldf8(Uj + m0, w);
#pragma unroll
        for (int tt = 0; tt < 16; ++tt) {
          float e[8]; ldf8(Eb + (size_t)(t0 + tt) * MM + m0, e);
#pragma unroll
          for (int mm = 0; mm < 8; ++mm) acc[tt] = fmaf(e[mm], w[mm], acc[tt]);
        }
      }
#pragma unroll
      for (int tt = 0; tt < 16; ++tt)
        y1l[rs][(t0 + tt) * YS + n] = f2h(acc[tt]);
    }
  }
  __syncthreads();

  // ---- gates: torch LSTMCell order i,f,g,o; j<256 threads, both rows ----
  auto gates_apply = [&](int r, float gi, float gf, float gg, float go,
                         float ytil) {
    gi += ytil * wih0 + bb0;
    gf += ytil * wih1 + bb1;
    gg += ytil * wih2 + bb2;
    go += ytil * wih3 + bb3;
    float& cr = r ? creg1 : creg0;
    float c = sigmoid_fast(gf) * cr + sigmoid_fast(gi) * tanh_fast(gg);
    float h = sigmoid_fast(go) * tanh_fast(c);
    cr = c;
    u16* hsu = (u16*)hs16[r];
    hsu[n] = f2h(h);
    hsu[256 + n] = f2h(c);
  };

  // ---- S2: Whh@h all 4 gates x both rows; waves 8-15; PEELED paths ----
  auto whh_gates = [&]() {
    if (wv >= 8) {
      const int jj = j - 512;
      const int n2 = jj & 255, half = jj >> 8;   // k-half
      float a00 = 0, a01 = 0, a10 = 0, a11 = 0;
      float a20 = 0, a21 = 0, a30 = 0, a31 = 0;
      if (WQ) {
        if (half == 0) {
          // kb 0..3 from LDS cache
          const u16* __restrict__ lb = whhc + (size_t)n2 * 8;
#pragma unroll
          for (int i = 0; i < 4; ++i) {
            const u16* p = lb + (size_t)i * 8192;
            H8 w0 = *(const H8*)p;
            H8 w1 = *(const H8*)(p + 2048);
            H8 w2 = *(const H8*)(p + 4096);
            H8 w3 = *(const H8*)(p + 6144);
            H8 h0v = *(const H8*)&hs16[0][i * 4];
            H8 h1v = *(const H8*)&hs16[1][i * 4];
            a00 = dot8(w0, h0v, a00); a01 = dot8(w0, h1v, a01);
            a10 = dot8(w1, h0v, a10); a11 = dot8(w1, h1v, a11);
            a20 = dot8(w2, h0v, a20); a21 = dot8(w2, h1v, a21);
            a30 = dot8(w3, h0v, a30); a31 = dot8(w3, h1v, a31);
          }
          // kb 4..15 from global
          const u16* __restrict__ base = (const u16*)Whh_q + (size_t)n2 * 8;
#pragma unroll 2
          for (int i = 4; i < 16; ++i) {
            const u16* p = base + (size_t)i * 8192;
            H8 w0 = *(const H8*)p;
            H8 w1 = *(const H8*)(p + 2048);
            H8 w2 = *(const H8*)(p + 4096);
            H8 w3 = *(const H8*)(p + 6144);
            H8 h0v = *(const H8*)&hs16[0][i * 4];
            H8 h1v = *(const H8*)&hs16[1][i * 4];
            a00 = dot8(w0, h0v, a00); a01 = dot8(w0, h1v, a01);
            a10 = dot8(w1, h0v, a10); a11 = dot8(w1, h1v, a11);
            a20 = dot8(w2, h0v, a20); a21 = dot8(w2, h1v, a21);
            a30 = dot8(w3, h0v, a30); a31 = dot8(w3, h1v, a31);
          }
        } else {
          // kb 16..31 from global
          const u16* __restrict__ base =
              (const u16*)Whh_q + ((size_t)16 * 1024 + n2) * 8;
#pragma unroll 2
          for (int i = 0; i < 16; ++i) {
            const u16* p = base + (size_t)i * 8192;
            H8 w0 = *(const H8*)p;
            H8 w1 = *(const H8*)(p + 2048);
            H8 w2 = *(const H8*)(p + 4096);
            H8 w3 = *(const H8*)(p + 6144);
            const int kb = 16 + i;
            H8 h0v = *(const H8*)&hs16[0][kb * 4];
            H8 h1v = *(const H8*)&hs16[1][kb * 4];
            a00 = dot8(w0, h0v, a00); a01 = dot8(w0, h1v, a01);
            a10 = dot8(w1, h0v, a10); a11 = dot8(w1, h1v, a11);
            a20 = dot8(w2, h0v, a20); a21 = dot8(w2, h1v, a21);
            a30 = dot8(w3, h0v, a30); a31 = dot8(w3, h1v, a31);
          }
        }
      } else {
        const float* __restrict__ base =
            (const float*)Whh_q + (size_t)n2 * 256 + half * 128;
#pragma unroll 2
        for (int i = 0; i < 16; ++i) {
          const int kb = half * 16 + i;
          H8 h0v = *(const H8*)&hs16[0][kb * 4];
          H8 h1v = *(const H8*)&hs16[1][kb * 4];
          float hf0[8], hf1[8]; unpackH8(h0v, hf0); unpackH8(h1v, hf1);
          float w0[8], w1[8], w2[8], w3[8];
          ldf8(base + i * 8, w0);
          ldf8(base + 256 * 256 + i * 8, w1);
          ldf8(base + 512 * 256 + i * 8, w2);
          ldf8(base + 768 * 256 + i * 8, w3);
#pragma unroll
          for (int m = 0; m < 8; ++m) {
            a00 = fmaf(hf0[m], w0[m], a00); a01 = fmaf(hf1[m], w0[m], a01);
            a10 = fmaf(hf0[m], w1[m], a10); a11 = fmaf(hf1[m], w1[m], a11);
            a20 = fmaf(hf0[m], w2[m], a20); a21 = fmaf(hf1[m], w2[m], a21);
            a30 = fmaf(hf0[m], w3[m], a30); a31 = fmaf(hf1[m], w3[m], a31);
          }
        }
      }
      pgs32[(0 << 1) | half][n2] = pack2h(a00, a01);
      pgs32[(1 << 1) | half][n2] = pack2h(a10, a11);
      pgs32[(2 << 1) | half][n2] = pack2h(a20, a21);
      pgs32[(3 << 1) | half][n2] = pack2h(a30, a31);
    }
  };

  // ---- G: combine pgs32 halves + LSTM gates (j<256, both rows) ----
  auto gates_combine_apply = [&](float yt0, float yt1) {
    h2 i0 = u2h2(pgs32[0][n]), i1 = u2h2(pgs32[1][n]);
    h2 f0 = u2h2(pgs32[2][n]), f1 = u2h2(pgs32[3][n]);
    h2 g0 = u2h2(pgs32[4][n]), g1 = u2h2(pgs32[5][n]);
    h2 o0 = u2h2(pgs32[6][n]), o1 = u2h2(pgs32[7][n]);
    gates_apply(0, (float)i0[0] + (float)i1[0], (float)f0[0] + (float)f1[0],
                (float)g0[0] + (float)g1[0], (float)o0[0] + (float)o1[0], yt0);
    gates_apply(1, (float)i0[1] + (float)i1[1], (float)f0[1] + (float)f1[1],
                (float)g0[1] + (float)g1[1], (float)o0[1] + (float)o1[1], yt1);
  };

  // ---- head: grp = (row<<1)|seg; seg0 = h-seg, seg1 = ct-seg ----
  auto head_store = [&](int outIdx) {
    float p = 0.f;
    const int rr = grp >> 1, seg = grp & 1;
    const u32* st = seg ? ctx16p[rr] : hs16[rr];
    if (WQ) {
      const u16* pw = (const u16*)Wy_q + ((size_t)(seg * 32) * 256 + n) * 8;
#pragma unroll 2
      for (int kb = 0; kb < 32; ++kb) {
        H8 w = *(const H8*)pw; pw += 2048;
        H8 s = *(const H8*)&st[kb * 4];
        p = dot8(w, s, p);
      }
    } else {
      const float* W = (const float*)Wy_q + (size_t)n * 512 + seg * 256;
#pragma unroll 2
      for (int kb = 0; kb < 32; ++kb) {
        H8 sv = *(const H8*)&st[kb * 4];
        float sf[8]; unpackH8(sv, sf);
        float w[8]; ldf8(W + kb * 8, w);
#pragma unroll
        for (int i = 0; i < 8; ++i) p = fmaf(sf[i], w[i], p);
      }
    }
    if (grp) px1[grp - 1][n] = p;   // px1 free after scan; reuse as head parts
    __syncthreads();
    if (grp == 0) {
      float q0 = (p + px1[0][n] + Wy_b[n]) * vy_w[n];
      float q1 = (px1[1][n] + px1[2][n] + Wy_b[n]) * vy_w[n];
#pragma unroll
      for (int off = 32; off; off >>= 1) {
        q0 += __shfl_xor(q0, off, 64);
        q1 += __shfl_xor(q1, off, 64);
      }
      if ((j & 63) == 0) { red[wv] = q0; red[8 + wv] = q1; }
    }
    __syncthreads();
    if (j == 0) {
      float o0 = red[0] + red[1] + red[2] + red[3] + vy_b[0];
      float o1 = red[8] + red[9] + red[10] + red[11] + vy_b[0];
      out[(size_t)outIdx * BB + b0] = o0;
      out[(size_t)outIdx * BB + b0 + 1] = o1;
      sc[0] = o0; sc[1] = o1;
    }
    __syncthreads();
  };

  // ================= scan over T steps =================
  for (int step = 0; step < TT; ++step) {
    // ---- S1: x1 = Wd.[h|c], 4-way split-k (all waves) ----
    {
      float ax0 = 0.f, ax1 = 0.f;
      if (WQ) {
        const u16* pd = (const u16*)Wd_q + ((size_t)(grp * 16) * 256 + n) * 8;
#pragma unroll 4
        for (int i = 0; i < 16; ++i) {
          H8 w = *(const H8*)pd; pd += 2048;
          const int kb = grp * 16 + i;
          H8 s0 = *(const H8*)&hs16[0][kb * 4];
          H8 s1 = *(const H8*)&hs16[1][kb * 4];
          ax0 = dot8(w, s0, ax0);
          ax1 = dot8(w, s1, ax1);
        }
      } else {
        const float* pd = (const float*)Wd_q + (size_t)n * 512 + grp * 128;
#pragma unroll 2
        for (int i = 0; i < 16; ++i) {
          const int kb = grp * 16 + i;
          H8 s0v = *(const H8*)&hs16[0][kb * 4];
          H8 s1v = *(const H8*)&hs16[1][kb * 4];
          float f0[8], f1[8]; unpackH8(s0v, f0); unpackH8(s1v, f1);
          float w[8]; ldf8(pd + i * 8, w);
#pragma unroll
          for (int m = 0; m < 8; ++m) {
            ax0 = fmaf(f0[m], w[m], ax0);
            ax1 = fmaf(f1[m], w[m], ax1);
          }
        }
      }
      if (grp == 0) { float b = Wd_b[n]; ax0 += b; ax1 += b; }
      px1[grp][n] = ax0;
      px1[4 + grp][n] = ax1;
    }
    __syncthreads();

    // ---- B1 (waves 0-7) PARALLEL S2 (waves 8-15) ----
    if (wv < 8) {
      const int r = j >> 8, e4 = (j >> 6) & 3, t = j & 63;
      const int mb = e4 * 64;
      const u16* __restrict__ yrow = &y1l[r][t * YS + mb];
      const float* __restrict__ p0 = &px1[(r << 2) | 0][mb];
      const float* __restrict__ p1 = &px1[(r << 2) | 1][mb];
      const float* __restrict__ p2 = &px1[(r << 2) | 2][mb];
      const float* __restrict__ p3 = &px1[(r << 2) | 3][mb];
      const float* __restrict__ vp = vd_w + mb;
      float lp = 0.f;
#pragma unroll 2
      for (int m0 = 0; m0 < 64; m0 += 8) {
        float xa[8], xb[8], xc[8], xd[8], vf[8], yf[8];
        ldf8(p0 + m0, xa); ldf8(p1 + m0, xb);
        ldf8(p2 + m0, xc); ldf8(p3 + m0, xd);
        H8 yv = *(const H8*)(yrow + m0); unpackH8(yv, yf);
        ldf8(vp + m0, vf);
#pragma unroll
        for (int mm = 0; mm < 8; ++mm) {
          float z = tanh_fast(xa[mm] + xb[mm] + xc[mm] + xd[mm] + yf[mm]);
          lp = fmaf(z, vf[mm], lp);
        }
      }
      lpart[r][e4][t] = lp;
    } else {
      whh_gates();
    }
    __syncthreads();

    // ---- SMG: in-wave softmax + ytil + gates (waves 0-3, both rows) ----
    if (j < 256) {
      const int t = j & 63;
      float l0 = lpart[0][0][t] + lpart[0][1][t] + lpart[0][2][t] +
                 lpart[0][3][t];
      float l1 = lpart[1][0][t] + lpart[1][1][t] + lpart[1][2][t] +
                 lpart[1][3][t];
      float m0v = l0, m1v = l1;
#pragma unroll
      for (int off = 32; off; off >>= 1) {
        m0v = fmaxf(m0v, __shfl_xor(m0v, off, 64));
        m1v = fmaxf(m1v, __shfl_xor(m1v, off, 64));
      }
      float e0 = __builtin_amdgcn_exp2f((l0 - m0v) * 1.4426950408889634f);
      float e1 = __builtin_amdgcn_exp2f((l1 - m1v) * 1.4426950408889634f);
      float se0 = e0, sy0 = e0 * ewl[0][t];
      float se1 = e1, sy1 = e1 * ewl[1][t];
#pragma unroll
      for (int off = 32; off; off >>= 1) {
        se0 += __shfl_xor(se0, off, 64); sy0 += __shfl_xor(sy0, off, 64);
        se1 += __shfl_xor(se1, off, 64); sy1 += __shfl_xor(sy1, off, 64);
      }
      float yt0 = sy0 * __builtin_amdgcn_rcpf(se0) + ysh[0][step] * wtM + wtb;
      float yt1 = sy1 * __builtin_amdgcn_rcpf(se1) + ysh[1][step] * wtM + wtb;
      gates_combine_apply(yt0, yt1);
    }
    __syncthreads();
  }

  // ================= finals =================
  // final beta (f32) from last step's lpart (waves 0-1)
  if (j < NROW * TT) {
    const int r = j >> 6, t = j & 63;
    float l = lpart[r][0][t] + lpart[r][1][t] + lpart[r][2][t] +
              lpart[r][3][t];
    float mx = l;
#pragma unroll
    for (int off = 32; off; off >>= 1) mx = fmaxf(mx, __shfl_xor(mx, off, 64));
    float e = __builtin_amdgcn_exp2f((l - mx) * 1.4426950408889634f);
    float sm = e;
#pragma unroll
    for (int off = 32; off; off >>= 1) sm += __shfl_xor(sm, off, 64);
    bet[r][t] = e * __builtin_amdgcn_rcpf(sm);
  }
  __syncthreads();

  // ct[n] = sum_t bet[t]*E[t][n] from GLOBAL E (f32; coalesced per t)
  if (j < 512) {
    const int r = j >> 8;
    const float* __restrict__ Eb = E + (size_t)(b0 + r) * TT * MM + n;
    float acc = 0.f;
#pragma unroll 8
    for (int t = 0; t < TT; ++t)
      acc = fmaf(bet[r][t], Eb[(size_t)t * MM], acc);
    ((u16*)ctx16p[r])[n] = f2h(acc);
    float p = acc * wt_w[n];
#pragma unroll
    for (int off = 32; off; off >>= 1) p += __shfl_xor(p, off, 64);
    if ((j & 63) == 0) red[wv] = p;   // wv 0..3 -> r0, 4..7 -> r1
  }
  __syncthreads();
  const float ctd0 = red[0] + red[1] + red[2] + red[3];
  const float ctd1 = red[4] + red[5] + red[6] + red[7];

  head_store(0);  // y_Tp1 (sc[] holds it for train==0 feedback)

  const int tr = train[0];
  for (int e = 0; e < 2; ++e) {
    whh_gates();            // waves 8-15: Whh@h -> pgs32
    __syncthreads();
    if (j < 256) {
      float inp0 = tr ? tar[(size_t)b0 * 2 + e] : sc[0];
      float inp1 = tr ? tar[(size_t)(b0 + 1) * 2 + e] : sc[1];
      float yt0 = ctd0 + inp0 * wtM + wtb;
      float yt1 = ctd1 + inp1 * wtM + wtb;
      gates_combine_apply(yt0, yt1);
    }
    __syncthreads();
    head_store(1 + e);
  }
}

extern "C" void kernel_launch(void* const* d_in, const int* in_sizes, int n_in,
                              void* d_out, int out_size, void* d_ws, size_t ws_size,
                              hipStream_t stream) {
  const float* E     = (const float*)d_in[0];
  const float* yin   = (const float*)d_in[1];
  const float* tar   = (const float*)d_in[2];
  const int*   train = (const int*)d_in[3];
  const float* Wd_w  = (const float*)d_in[4];
  const float* Wd_b  = (const float*)d_in[5];
  const float* Ud_w  = (const float*)d_in[6];
  const float* vd_w  = (const float*)d_in[7];
  const float* wt_w  = (const float*)d_in[8];
  const float* wt_b  = (const float*)d_in[9];
  const float* Wy_w  = (const float*)d_in[10];
  const float* Wy_b  = (const float*)d_in[11];
  const float* vy_w  = (const float*)d_in[12];
  const float* vy_b  = (const float*)d_in[13];
  const float* Wih   = (const float*)d_in[14];
  const float* Whh   = (const float*)d_in[15];
  const float* bih   = (const float*)d_in[16];
  const float* bhh   = (const float*)d_in[17];

  float* out = (float*)d_out;

  if (ws_size >= (size_t)WQ_BYTES) {
    u16* wq = (u16*)d_ws;
    prep_kernel<<<dim3(WQ_ELEMS / 256), dim3(256), 0, stream>>>(
        Wd_w, Whh, Wy_w, wq);
    scan_kernel<1><<<dim3(BB / NROW), dim3(NTH), 0, stream>>>(
        E, yin, tar, train, wq + WD16_OFF, Wd_b, Ud_w, vd_w, wt_w, wt_b,
        wq + WY16_OFF, Wy_b, vy_w, vy_b, Wih, wq + WHH16_OFF, bih, bhh, out);
  } else {
    scan_kernel<0><<<dim3(BB / NROW), dim3(NTH), 0, stream>>>(
        E, yin, tar, train, Wd_w, Wd_b, Ud_w, vd_w, wt_w, wt_b,
        Wy_w, Wy_b, vy_w, vy_b, Wih, Whh, bih, bhh, out);
  }

  (void)in_sizes; (void)n_in; (void)out_size;
}